// Round 1
// baseline (251.567 us; speedup 1.0000x reference)
//
#include <hip/hip_runtime.h>

#define NGRAPH 512
#define NPG    256
#define KPG    128
#define NN     (NGRAPH * NPG)   // 131072 nodes
#define KK     (NGRAPH * KPG)   // 65536 kept nodes
#define NE     4194304          // edges
#define DF     128
#define DE     16
#define EBLK   256
#define NEBLK  (NE / EBLK)      // 16384 edge blocks

// output layout (float32 elements, concatenated in reference return order)
#define OUT_X     0ull
#define OUT_EI    ((size_t)KK * DF)                 // 8388608
#define OUT_ATTR  (OUT_EI + 2ull * NE)              // 16777216
#define OUT_BATCH (OUT_ATTR + (size_t)NE * DE)      // 83886080
#define OUT_PERM  (OUT_BATCH + KK)
#define OUT_W     (OUT_PERM + KK)

// --- 1. scores = x @ W + b; node_map = -1 --------------------------------
__global__ void score_kernel(const float* __restrict__ x,
                             const float* __restrict__ W,
                             const float* __restrict__ b,
                             float* __restrict__ scores,
                             int* __restrict__ node_map) {
    int gtid = blockIdx.x * blockDim.x + threadIdx.x;
    int node = gtid >> 6;
    int lane = threadIdx.x & 63;
    if (node >= NN) return;
    const float* row = x + (size_t)node * DF;
    float2 xv = *(const float2*)(row + lane * 2);
    float2 wv = *(const float2*)(W + lane * 2);
    float s = xv.x * wv.x + xv.y * wv.y;
    #pragma unroll
    for (int off = 32; off > 0; off >>= 1) s += __shfl_down(s, off, 64);
    if (lane == 0) {
        scores[node] = s + b[0];
        node_map[node] = -1;
    }
}

// --- 2. per-graph top-k (rank by value desc, index asc) ------------------
__global__ void topk_kernel(const float* __restrict__ scores,
                            int* __restrict__ perm_i,
                            float* __restrict__ w_f,
                            int* __restrict__ node_map) {
    __shared__ float s[NPG];
    int g = blockIdx.x, t = threadIdx.x;
    float my = scores[g * NPG + t];
    s[t] = my;
    __syncthreads();
    int rank = 0;
    #pragma unroll 8
    for (int j = 0; j < NPG; j++) {
        float o = s[j];
        rank += (o > my) || (o == my && j < t);
    }
    if (rank < KPG) {
        int node = g * NPG + t;
        int nid  = g * KPG + rank;
        perm_i[nid] = node;
        w_f[nid]    = my;
        node_map[node] = nid;
    }
}

// --- 3. x_out = x[perm]*w ; batch/perm/w outputs -------------------------
__global__ void gather_kernel(const float* __restrict__ x,
                              const int* __restrict__ perm_i,
                              const float* __restrict__ w_f,
                              float* __restrict__ out) {
    int i = blockIdx.x * 2 + (threadIdx.x >> 7);   // output row
    int d = threadIdx.x & 127;
    int p = perm_i[i];
    float wv = w_f[i];
    out[OUT_X + (size_t)i * DF + d] = x[(size_t)p * DF + d] * wv;
    if (d == 0) {
        out[OUT_BATCH + i] = (float)(p >> 8);   // p / NPG
        out[OUT_PERM + i]  = (float)p;
        out[OUT_W + i]     = wv;
    }
}

// --- 4. fill new_ei = -1, new_attr = 0 -----------------------------------
__global__ void fill_kernel(float* __restrict__ out) {
    const size_t ei4    = (2ull * NE) / 4;
    const size_t total4 = (2ull * NE + (size_t)NE * DE) / 4;
    float4* base = (float4*)(out + OUT_EI);
    float4 neg1 = make_float4(-1.f, -1.f, -1.f, -1.f);
    float4 zero = make_float4(0.f, 0.f, 0.f, 0.f);
    size_t stride = (size_t)gridDim.x * blockDim.x;
    for (size_t i = (size_t)blockIdx.x * blockDim.x + threadIdx.x; i < total4; i += stride)
        base[i] = (i < ei4) ? neg1 : zero;
}

// --- 5. per-block kept-edge counts ---------------------------------------
__global__ void count_kernel(const int* __restrict__ ei,
                             const int* __restrict__ node_map,
                             int* __restrict__ blocksums) {
    int e = blockIdx.x * EBLK + threadIdx.x;
    bool m = (node_map[ei[e]] >= 0) && (node_map[ei[NE + e]] >= 0);
    unsigned long long bal = __ballot(m);
    __shared__ int cnt[4];
    int wave = threadIdx.x >> 6, lane = threadIdx.x & 63;
    if (lane == 0) cnt[wave] = __popcll(bal);
    __syncthreads();
    if (threadIdx.x == 0)
        blocksums[blockIdx.x] = cnt[0] + cnt[1] + cnt[2] + cnt[3];
}

// --- 6. exclusive scan of 16384 block sums (single block) ----------------
__global__ void scan_kernel(const int* __restrict__ blocksums,
                            int* __restrict__ blockoffs) {
    const int PER = NEBLK / 256;   // 64
    int t = threadIdx.x;
    int base = t * PER;
    int s = 0;
    for (int j = 0; j < PER; j++) s += blocksums[base + j];
    __shared__ int ls[256];
    ls[t] = s;
    __syncthreads();
    for (int off = 1; off < 256; off <<= 1) {
        int v = (t >= off) ? ls[t - off] : 0;
        __syncthreads();
        ls[t] += v;
        __syncthreads();
    }
    int run = ls[t] - s;   // exclusive prefix of this thread's chunk
    for (int j = 0; j < PER; j++) {
        int c = blocksums[base + j];
        blockoffs[base + j] = run;
        run += c;
    }
}

// --- 7. stable scatter of kept edges -------------------------------------
__global__ void scatter_kernel(const int* __restrict__ ei,
                               const float* __restrict__ eattr,
                               const int* __restrict__ node_map,
                               const int* __restrict__ blockoffs,
                               float* __restrict__ out) {
    int e = blockIdx.x * EBLK + threadIdx.x;
    int ns = node_map[ei[e]];
    int nd = node_map[ei[NE + e]];
    bool m = (ns >= 0) && (nd >= 0);
    unsigned long long bal = __ballot(m);
    __shared__ int wcnt[4];
    int wave = threadIdx.x >> 6, lane = threadIdx.x & 63;
    if (lane == 0) wcnt[wave] = __popcll(bal);
    __syncthreads();
    if (m) {
        int wbase = 0;
        for (int i = 0; i < wave; i++) wbase += wcnt[i];
        int lpre = __popcll(bal & ((1ull << lane) - 1ull));
        int pos = blockoffs[blockIdx.x] + wbase + lpre;
        out[OUT_EI + pos]      = (float)ns;
        out[OUT_EI + NE + pos] = (float)nd;
        const float4* srcp = (const float4*)(eattr + (size_t)e * DE);
        float4* dstp = (float4*)(out + OUT_ATTR + (size_t)pos * DE);
        #pragma unroll
        for (int j = 0; j < DE / 4; j++) dstp[j] = srcp[j];
    }
}

extern "C" void kernel_launch(void* const* d_in, const int* in_sizes, int n_in,
                              void* d_out, int out_size, void* d_ws, size_t ws_size,
                              hipStream_t stream) {
    const float* x     = (const float*)d_in[0];
    const int*   ei    = (const int*)d_in[1];
    const float* eattr = (const float*)d_in[2];
    const float* W     = (const float*)d_in[4];
    const float* b     = (const float*)d_in[5];
    float* out = (float*)d_out;

    // workspace layout
    float* scores   = (float*)d_ws;
    int*   node_map = (int*)d_ws + NN;
    int*   perm_i   = node_map + NN;
    float* w_f      = (float*)(perm_i + KK);
    int*   blocksums = (int*)(w_f + KK);
    int*   blockoffs = blocksums + NEBLK;

    score_kernel  <<<NN / 4, 256, 0, stream>>>(x, W, b, scores, node_map);
    topk_kernel   <<<NGRAPH, 256, 0, stream>>>(scores, perm_i, w_f, node_map);
    gather_kernel <<<KK / 2, 256, 0, stream>>>(x, perm_i, w_f, out);
    fill_kernel   <<<4096, 256, 0, stream>>>(out);
    count_kernel  <<<NEBLK, EBLK, 0, stream>>>(ei, node_map, blocksums);
    scan_kernel   <<<1, 256, 0, stream>>>(blocksums, blockoffs);
    scatter_kernel<<<NEBLK, EBLK, 0, stream>>>(ei, eattr, node_map, blockoffs, out);
}

// Round 2
// 223.882 us; speedup vs baseline: 1.1237x; 1.1237x over previous
//
#include <hip/hip_runtime.h>

#define NGRAPH 512
#define NPG    256
#define KPG    128
#define NN     (NGRAPH * NPG)   // 131072 nodes
#define KK     (NGRAPH * KPG)   // 65536 kept nodes
#define NE     4194304          // edges
#define DF     128
#define DE     16

#define SBLK   256              // threads per scan block
#define VPT    4                // sub-batches of 256 edges per block
#define EPB    (SBLK * VPT)     // 1024 edges per block
#define NTILE  (NE / EPB)       // 4096 tiles

// output layout (float32 elements, concatenated in reference return order)
#define OUT_X     0ull
#define OUT_EI    ((size_t)KK * DF)                 // 8388608
#define OUT_ATTR  (OUT_EI + 2ull * NE)              // 16777216
#define OUT_BATCH (OUT_ATTR + (size_t)NE * DE)      // 83886080
#define OUT_PERM  (OUT_BATCH + KK)
#define OUT_W     (OUT_PERM + KK)

// --- 1. scores = x @ W + b (float4, 32 lanes/row); node_map=-1; status=0 --
__global__ void score_kernel(const float* __restrict__ x,
                             const float* __restrict__ W,
                             const float* __restrict__ b,
                             float* __restrict__ scores,
                             int* __restrict__ node_map,
                             unsigned long long* __restrict__ tilestatus) {
    int t = threadIdx.x;
    int half = t >> 5;               // 0..7 : row within block
    int l32 = t & 31;
    int node = blockIdx.x * 8 + half;
    float4 xv = ((const float4*)(x + (size_t)node * DF))[l32];
    float4 wv = ((const float4*)W)[l32];
    float s = xv.x * wv.x + xv.y * wv.y + xv.z * wv.z + xv.w * wv.w;
    #pragma unroll
    for (int off = 16; off > 0; off >>= 1) s += __shfl_down(s, off, 32);
    if (l32 == 0) {
        scores[node] = s + b[0];
        node_map[node] = -1;
    }
    int gtid = blockIdx.x * blockDim.x + t;
    if (gtid < NTILE) tilestatus[gtid] = 0ull;
}

// --- 2. per-graph top-k (rank = value desc, index asc) -------------------
__global__ void topk_kernel(const float* __restrict__ scores,
                            int* __restrict__ perm_i,
                            float* __restrict__ w_f,
                            int* __restrict__ node_map) {
    __shared__ float s[NPG];
    int g = blockIdx.x, t = threadIdx.x;
    float my = scores[g * NPG + t];
    s[t] = my;
    __syncthreads();
    int rank = 0;
    #pragma unroll 8
    for (int j = 0; j < NPG; j++) {
        float o = s[j];
        rank += (o > my) || (o == my && j < t);
    }
    if (rank < KPG) {
        int node = g * NPG + t;
        int nid  = g * KPG + rank;
        perm_i[nid] = node;
        w_f[nid]    = my;
        node_map[node] = nid;
    }
}

// --- 3. x_out = x[perm]*w (float4); batch/perm/w outputs -----------------
__global__ void gather_kernel(const float* __restrict__ x,
                              const int* __restrict__ perm_i,
                              const float* __restrict__ w_f,
                              float* __restrict__ out) {
    int t = threadIdx.x;
    int i = blockIdx.x * 8 + (t >> 5);   // output row
    int d4 = t & 31;                     // float4 index within row
    int p = perm_i[i];
    float wv = w_f[i];
    float4 v = ((const float4*)(x + (size_t)p * DF))[d4];
    v.x *= wv; v.y *= wv; v.z *= wv; v.w *= wv;
    ((float4*)(out + OUT_X + (size_t)i * DF))[d4] = v;
    if (d4 == 0) {
        out[OUT_BATCH + i] = (float)(p >> 8);   // p / NPG
        out[OUT_PERM + i]  = (float)p;
        out[OUT_W + i]     = wv;
    }
}

// --- 4. single-pass decoupled-lookback scan + stable scatter -------------
__global__ void __launch_bounds__(SBLK)
scan_scatter_kernel(const int* __restrict__ ei,
                    const float* __restrict__ eattr,
                    const int* __restrict__ node_map,
                    unsigned long long* __restrict__ tilestatus,
                    int* __restrict__ d_total,
                    float* __restrict__ out) {
    int tile = blockIdx.x;
    int t = threadIdx.x;
    int wave = t >> 6, lane = t & 63;
    __shared__ int subcnt[VPT][4];
    __shared__ int s_excl;

    int ns[VPT], nd[VPT];
    bool m[VPT];
    unsigned long long bal[VPT];
    int ebase = tile * EPB;
    #pragma unroll
    for (int v = 0; v < VPT; v++) {
        int e = ebase + v * SBLK + t;
        int a = ei[e], c = ei[NE + e];
        ns[v] = node_map[a];
        nd[v] = node_map[c];
        m[v] = (ns[v] >= 0) && (nd[v] >= 0);
        bal[v] = __ballot(m[v]);
        if (lane == 0) subcnt[v][wave] = __popcll(bal[v]);
    }
    __syncthreads();
    int cnt = 0;
    #pragma unroll
    for (int v = 0; v < VPT; v++)
        cnt += subcnt[v][0] + subcnt[v][1] + subcnt[v][2] + subcnt[v][3];

    if (t < 64) {  // wave 0: decoupled lookback
        if (tile == 0) {
            if (lane == 0) {
                __hip_atomic_store(&tilestatus[0],
                    (2ull << 32) | (unsigned)cnt,
                    __ATOMIC_RELAXED, __HIP_MEMORY_SCOPE_AGENT);
                s_excl = 0;
            }
        } else {
            if (lane == 0)
                __hip_atomic_store(&tilestatus[tile],
                    (1ull << 32) | (unsigned)cnt,
                    __ATOMIC_RELAXED, __HIP_MEMORY_SCOPE_AGENT);
            int running = 0;
            int look = tile;
            for (;;) {
                int idx = look - 1 - lane;
                unsigned long long st = 0ull;
                if (idx >= 0)
                    st = __hip_atomic_load(&tilestatus[idx],
                        __ATOMIC_RELAXED, __HIP_MEMORY_SCOPE_AGENT);
                unsigned flag = (unsigned)(st >> 32);
                int val = (int)(unsigned)st;
                bool valid = idx >= 0;
                unsigned long long m0 = __ballot(valid && flag == 0u);
                unsigned long long m2 = __ballot(valid && flag == 2u);
                if (m2) {
                    int f = __ffsll((long long)m2) - 1;    // nearest inclusive
                    if (m0 & ((1ull << f) - 1ull)) continue;  // gap -> retry
                    int contrib = (lane <= f) ? val : 0;
                    #pragma unroll
                    for (int off = 32; off > 0; off >>= 1)
                        contrib += __shfl_down(contrib, off, 64);
                    running += __shfl(contrib, 0, 64);
                    break;
                } else {
                    if (m0) continue;                       // retry window
                    int contrib = valid ? val : 0;
                    #pragma unroll
                    for (int off = 32; off > 0; off >>= 1)
                        contrib += __shfl_down(contrib, off, 64);
                    running += __shfl(contrib, 0, 64);
                    look -= 64;
                    if (look <= 0) break;
                }
            }
            if (lane == 0) {
                __hip_atomic_store(&tilestatus[tile],
                    (2ull << 32) | (unsigned)(cnt + running),
                    __ATOMIC_RELAXED, __HIP_MEMORY_SCOPE_AGENT);
                s_excl = running;
            }
        }
    }
    __syncthreads();
    int excl = s_excl;
    if (tile == NTILE - 1 && t == 0) d_total[0] = excl + cnt;

    int sub_off = excl;
    #pragma unroll
    for (int v = 0; v < VPT; v++) {
        if (m[v]) {
            int wbase = 0;
            for (int i = 0; i < wave; i++) wbase += subcnt[v][i];
            int lpre = __popcll(bal[v] & ((1ull << lane) - 1ull));
            int pos = sub_off + wbase + lpre;
            out[OUT_EI + pos]      = (float)ns[v];
            out[OUT_EI + NE + pos] = (float)nd[v];
            int e = ebase + v * SBLK + t;
            const float4* sp = (const float4*)(eattr + (size_t)e * DE);
            float4* dp = (float4*)(out + OUT_ATTR + (size_t)pos * DE);
            dp[0] = sp[0]; dp[1] = sp[1]; dp[2] = sp[2]; dp[3] = sp[3];
        }
        sub_off += subcnt[v][0] + subcnt[v][1] + subcnt[v][2] + subcnt[v][3];
    }
}

// --- 5. tail fill: ei[-1] / attr[0] from total to NE ---------------------
__global__ void tailfill_kernel(const int* __restrict__ d_total,
                                float* __restrict__ out) {
    int total = d_total[0];
    size_t stride = (size_t)gridDim.x * blockDim.x;
    size_t tid = (size_t)blockIdx.x * blockDim.x + threadIdx.x;
    for (size_t i = (size_t)total + tid; i < NE; i += stride)
        out[OUT_EI + i] = -1.f;
    for (size_t i = (size_t)total + tid; i < NE; i += stride)
        out[OUT_EI + NE + i] = -1.f;
    float4* ap = (float4*)(out + OUT_ATTR);
    float4 z = make_float4(0.f, 0.f, 0.f, 0.f);
    for (size_t i = (size_t)total * 4 + tid; i < (size_t)NE * 4; i += stride)
        ap[i] = z;
}

extern "C" void kernel_launch(void* const* d_in, const int* in_sizes, int n_in,
                              void* d_out, int out_size, void* d_ws, size_t ws_size,
                              hipStream_t stream) {
    const float* x     = (const float*)d_in[0];
    const int*   ei    = (const int*)d_in[1];
    const float* eattr = (const float*)d_in[2];
    const float* W     = (const float*)d_in[4];
    const float* b     = (const float*)d_in[5];
    float* out = (float*)d_out;

    // workspace layout (8B-aligned first)
    unsigned long long* tilestatus = (unsigned long long*)d_ws;
    int*   d_total  = (int*)(tilestatus + NTILE);
    float* scores   = (float*)(d_total + 64);     // pad
    int*   node_map = (int*)(scores + NN);
    int*   perm_i   = node_map + NN;
    float* w_f      = (float*)(perm_i + KK);

    score_kernel  <<<NN / 8, 256, 0, stream>>>(x, W, b, scores, node_map, tilestatus);
    topk_kernel   <<<NGRAPH, 256, 0, stream>>>(scores, perm_i, w_f, node_map);
    gather_kernel <<<KK / 8, 256, 0, stream>>>(x, perm_i, w_f, out);
    scan_scatter_kernel<<<NTILE, SBLK, 0, stream>>>(ei, eattr, node_map, tilestatus, d_total, out);
    tailfill_kernel<<<2048, 256, 0, stream>>>(d_total, out);
}

// Round 3
// 221.667 us; speedup vs baseline: 1.1349x; 1.0100x over previous
//
#include <hip/hip_runtime.h>

#define NGRAPH 512
#define NPG    256
#define KPG    128
#define NN     (NGRAPH * NPG)   // 131072 nodes
#define KK     (NGRAPH * KPG)   // 65536 kept nodes
#define NE     4194304          // edges
#define DF     128
#define DE     16

#define SBLK   256              // threads per scan block
#define VPT    4                // sub-batches of 256 edges per block
#define EPB    (SBLK * VPT)     // 1024 edges per block
#define NTILE  (NE / EPB)       // 4096 tiles

// output layout (float32 elements, concatenated in reference return order)
#define OUT_X     0ull
#define OUT_EI    ((size_t)KK * DF)                 // 8388608
#define OUT_ATTR  (OUT_EI + 2ull * NE)              // 16777216
#define OUT_BATCH (OUT_ATTR + (size_t)NE * DE)      // 83886080
#define OUT_PERM  (OUT_BATCH + KK)
#define OUT_W     (OUT_PERM + KK)

// --- 1. scores = x @ W + b (float4, 32 lanes/row); node_map=-1; status=0 --
__global__ void score_kernel(const float* __restrict__ x,
                             const float* __restrict__ W,
                             const float* __restrict__ b,
                             float* __restrict__ scores,
                             int* __restrict__ node_map,
                             unsigned long long* __restrict__ tilestatus) {
    int t = threadIdx.x;
    int half = t >> 5;               // 0..7 : row within block
    int l32 = t & 31;
    int node = blockIdx.x * 8 + half;
    float4 xv = ((const float4*)(x + (size_t)node * DF))[l32];
    float4 wv = ((const float4*)W)[l32];
    float s = xv.x * wv.x + xv.y * wv.y + xv.z * wv.z + xv.w * wv.w;
    #pragma unroll
    for (int off = 16; off > 0; off >>= 1) s += __shfl_down(s, off, 32);
    if (l32 == 0) {
        scores[node] = s + b[0];
        node_map[node] = -1;
    }
    int gtid = blockIdx.x * blockDim.x + t;
    if (gtid < NTILE) tilestatus[gtid] = 0ull;
}

// --- 2. fused per-graph top-k + gather-scale + small outputs -------------
__global__ void __launch_bounds__(NPG)
topk_gather_kernel(const float* __restrict__ scores,
                   const float* __restrict__ x,
                   int* __restrict__ node_map,
                   float* __restrict__ out) {
    __shared__ float s[NPG];
    __shared__ int   sel[KPG];      // rank -> local node id
    __shared__ float selw[KPG];     // rank -> score
    int g = blockIdx.x, t = threadIdx.x;
    float my = scores[g * NPG + t];
    s[t] = my;
    __syncthreads();
    int rank = 0;
    #pragma unroll 8
    for (int j = 0; j < NPG; j++) {
        float o = s[j];
        rank += (o > my) || (o == my && j < t);
    }
    if (rank < KPG) {
        int node = g * NPG + t;
        int nid  = g * KPG + rank;
        node_map[node] = nid;
        sel[rank]  = t;
        selw[rank] = my;
        out[OUT_BATCH + nid] = (float)g;
        out[OUT_PERM + nid]  = (float)node;
        out[OUT_W + nid]     = my;
    }
    __syncthreads();
    // gather + scale: 8 rows in flight (32 lanes x float4 each), 16 iters
    int l32 = t & 31, rsub = t >> 5;
    #pragma unroll
    for (int it = 0; it < KPG / 8; it++) {
        int r = it * 8 + rsub;                 // rank (= output row within graph)
        int node = g * NPG + sel[r];
        float wv = selw[r];
        float4 v = ((const float4*)(x + (size_t)node * DF))[l32];
        v.x *= wv; v.y *= wv; v.z *= wv; v.w *= wv;
        ((float4*)(out + OUT_X + ((size_t)g * KPG + r) * DF))[l32] = v;
    }
}

// --- 3. single-pass lookback scan + stable scatter + fused tail fill -----
__global__ void __launch_bounds__(SBLK)
scan_scatter_kernel(const int* __restrict__ ei,
                    const float* __restrict__ eattr,
                    const int* __restrict__ node_map,
                    unsigned long long* __restrict__ tilestatus,
                    float* __restrict__ out) {
    int tile = blockIdx.x;
    int t = threadIdx.x;
    int wave = t >> 6, lane = t & 63;
    __shared__ int subcnt[VPT][4];
    __shared__ int s_excl;

    int ns[VPT], nd[VPT];
    bool m[VPT];
    unsigned long long bal[VPT];
    int ebase = tile * EPB;
    #pragma unroll
    for (int v = 0; v < VPT; v++) {
        int e = ebase + v * SBLK + t;
        int a = ei[e], c = ei[NE + e];
        ns[v] = node_map[a];
        nd[v] = node_map[c];
        m[v] = (ns[v] >= 0) && (nd[v] >= 0);
        bal[v] = __ballot(m[v]);
        if (lane == 0) subcnt[v][wave] = __popcll(bal[v]);
    }
    __syncthreads();
    int cnt = 0;
    #pragma unroll
    for (int v = 0; v < VPT; v++)
        cnt += subcnt[v][0] + subcnt[v][1] + subcnt[v][2] + subcnt[v][3];

    if (t < 64) {  // wave 0: decoupled lookback
        if (tile == 0) {
            if (lane == 0) {
                __hip_atomic_store(&tilestatus[0],
                    (2ull << 32) | (unsigned)cnt,
                    __ATOMIC_RELAXED, __HIP_MEMORY_SCOPE_AGENT);
                s_excl = 0;
            }
        } else {
            if (lane == 0)
                __hip_atomic_store(&tilestatus[tile],
                    (1ull << 32) | (unsigned)cnt,
                    __ATOMIC_RELAXED, __HIP_MEMORY_SCOPE_AGENT);
            int running = 0;
            int look = tile;
            for (;;) {
                int idx = look - 1 - lane;
                unsigned long long st = 0ull;
                if (idx >= 0)
                    st = __hip_atomic_load(&tilestatus[idx],
                        __ATOMIC_RELAXED, __HIP_MEMORY_SCOPE_AGENT);
                unsigned flag = (unsigned)(st >> 32);
                int val = (int)(unsigned)st;
                bool valid = idx >= 0;
                unsigned long long m0 = __ballot(valid && flag == 0u);
                unsigned long long m2 = __ballot(valid && flag == 2u);
                if (m2) {
                    int f = __ffsll((long long)m2) - 1;    // nearest inclusive
                    if (m0 & ((1ull << f) - 1ull)) continue;  // gap -> retry
                    int contrib = (lane <= f) ? val : 0;
                    #pragma unroll
                    for (int off = 32; off > 0; off >>= 1)
                        contrib += __shfl_down(contrib, off, 64);
                    running += __shfl(contrib, 0, 64);
                    break;
                } else {
                    if (m0) continue;                       // retry window
                    int contrib = valid ? val : 0;
                    #pragma unroll
                    for (int off = 32; off > 0; off >>= 1)
                        contrib += __shfl_down(contrib, off, 64);
                    running += __shfl(contrib, 0, 64);
                    look -= 64;
                    if (look <= 0) break;
                }
            }
            if (lane == 0) {
                __hip_atomic_store(&tilestatus[tile],
                    (2ull << 32) | (unsigned)(cnt + running),
                    __ATOMIC_RELAXED, __HIP_MEMORY_SCOPE_AGENT);
                s_excl = running;
            }
        }
    }
    __syncthreads();
    int excl = s_excl;

    // kept-edge scatter (stable)
    int sub_off = excl;
    #pragma unroll
    for (int v = 0; v < VPT; v++) {
        if (m[v]) {
            int wbase = 0;
            for (int i = 0; i < wave; i++) wbase += subcnt[v][i];
            int lpre = __popcll(bal[v] & ((1ull << lane) - 1ull));
            int pos = sub_off + wbase + lpre;
            out[OUT_EI + pos]      = (float)ns[v];
            out[OUT_EI + NE + pos] = (float)nd[v];
            int e = ebase + v * SBLK + t;
            const float4* sp = (const float4*)(eattr + (size_t)e * DE);
            float4* dp = (float4*)(out + OUT_ATTR + (size_t)pos * DE);
            dp[0] = sp[0]; dp[1] = sp[1]; dp[2] = sp[2]; dp[3] = sp[3];
        }
        sub_off += subcnt[v][0] + subcnt[v][1] + subcnt[v][2] + subcnt[v][3];
    }

    // fused tail fill: this tile's discarded edges own tail slots
    // [NE - disc_excl - disc_cnt, NE - disc_excl)
    int disc_excl = tile * EPB - excl;
    int disc_cnt  = EPB - cnt;
    size_t tail_lo = (size_t)NE - disc_excl - disc_cnt;
    for (int i = t; i < disc_cnt; i += SBLK) {
        out[OUT_EI + tail_lo + i]      = -1.f;
        out[OUT_EI + NE + tail_lo + i] = -1.f;
    }
    float4* ap = (float4*)(out + OUT_ATTR);
    float4 z = make_float4(0.f, 0.f, 0.f, 0.f);
    for (int i = t; i < disc_cnt * 4; i += SBLK)
        ap[tail_lo * 4 + i] = z;
}

extern "C" void kernel_launch(void* const* d_in, const int* in_sizes, int n_in,
                              void* d_out, int out_size, void* d_ws, size_t ws_size,
                              hipStream_t stream) {
    const float* x     = (const float*)d_in[0];
    const int*   ei    = (const int*)d_in[1];
    const float* eattr = (const float*)d_in[2];
    const float* W     = (const float*)d_in[4];
    const float* b     = (const float*)d_in[5];
    float* out = (float*)d_out;

    // workspace layout (8B-aligned first)
    unsigned long long* tilestatus = (unsigned long long*)d_ws;
    float* scores   = (float*)(tilestatus + NTILE);
    int*   node_map = (int*)(scores + NN);

    score_kernel      <<<NN / 8, 256, 0, stream>>>(x, W, b, scores, node_map, tilestatus);
    topk_gather_kernel<<<NGRAPH, NPG, 0, stream>>>(scores, x, node_map, out);
    scan_scatter_kernel<<<NTILE, SBLK, 0, stream>>>(ei, eattr, node_map, tilestatus, out);
}

// Round 4
// 221.343 us; speedup vs baseline: 1.1365x; 1.0015x over previous
//
#include <hip/hip_runtime.h>

#define NGRAPH 512
#define NPG    256
#define KPG    128
#define NN     (NGRAPH * NPG)   // 131072 nodes
#define KK     (NGRAPH * KPG)   // 65536 kept nodes
#define NE     4194304          // edges
#define DF     128
#define DE     16

#define SBLK   256              // threads per edge block
#define VPT    4                // sub-batches of 256 edges per block
#define EPB    (SBLK * VPT)     // 1024 edges per block
#define NTILE  (NE / EPB)       // 4096 tiles

// output layout (float32 elements, concatenated in reference return order)
#define OUT_X     0ull
#define OUT_EI    ((size_t)KK * DF)                 // 8388608
#define OUT_ATTR  (OUT_EI + 2ull * NE)              // 16777216
#define OUT_BATCH (OUT_ATTR + (size_t)NE * DE)      // 83886080
#define OUT_PERM  (OUT_BATCH + KK)
#define OUT_W     (OUT_PERM + KK)

// --- 1. scores = x @ W + b (float4, 32 lanes/row); node_map = -1 ---------
__global__ void score_kernel(const float* __restrict__ x,
                             const float* __restrict__ W,
                             const float* __restrict__ b,
                             float* __restrict__ scores,
                             int* __restrict__ node_map) {
    int t = threadIdx.x;
    int half = t >> 5;               // 0..7 : row within block
    int l32 = t & 31;
    int node = blockIdx.x * 8 + half;
    float4 xv = ((const float4*)(x + (size_t)node * DF))[l32];
    float4 wv = ((const float4*)W)[l32];
    float s = xv.x * wv.x + xv.y * wv.y + xv.z * wv.z + xv.w * wv.w;
    #pragma unroll
    for (int off = 16; off > 0; off >>= 1) s += __shfl_down(s, off, 32);
    if (l32 == 0) {
        scores[node] = s + b[0];
        node_map[node] = -1;
    }
}

// --- 2. fused per-graph top-k + gather-scale + small outputs -------------
__global__ void __launch_bounds__(NPG)
topk_gather_kernel(const float* __restrict__ scores,
                   const float* __restrict__ x,
                   int* __restrict__ node_map,
                   float* __restrict__ out) {
    __shared__ float s[NPG];
    __shared__ int   sel[KPG];      // rank -> local node id
    __shared__ float selw[KPG];     // rank -> score
    int g = blockIdx.x, t = threadIdx.x;
    float my = scores[g * NPG + t];
    s[t] = my;
    __syncthreads();
    int rank = 0;
    #pragma unroll 8
    for (int j = 0; j < NPG; j++) {
        float o = s[j];
        rank += (o > my) || (o == my && j < t);
    }
    if (rank < KPG) {
        int node = g * NPG + t;
        int nid  = g * KPG + rank;
        node_map[node] = nid;
        sel[rank]  = t;
        selw[rank] = my;
        out[OUT_BATCH + nid] = (float)g;
        out[OUT_PERM + nid]  = (float)node;
        out[OUT_W + nid]     = my;
    }
    __syncthreads();
    // gather + scale: 8 rows in flight (32 lanes x float4 each), 16 iters
    int l32 = t & 31, rsub = t >> 5;
    #pragma unroll
    for (int it = 0; it < KPG / 8; it++) {
        int r = it * 8 + rsub;                 // rank (= output row within graph)
        int node = g * NPG + sel[r];
        float wv = selw[r];
        float4 v = ((const float4*)(x + (size_t)node * DF))[l32];
        v.x *= wv; v.y *= wv; v.z *= wv; v.w *= wv;
        ((float4*)(out + OUT_X + ((size_t)g * KPG + r) * DF))[l32] = v;
    }
}

// --- 3. per-tile kept-edge counts ----------------------------------------
__global__ void __launch_bounds__(SBLK)
count_kernel(const int* __restrict__ ei,
             const int* __restrict__ node_map,
             int* __restrict__ tilecounts) {
    int tile = blockIdx.x;
    int t = threadIdx.x;
    int wave = t >> 6, lane = t & 63;
    __shared__ int subcnt[VPT][4];
    int ebase = tile * EPB;
    #pragma unroll
    for (int v = 0; v < VPT; v++) {
        int e = ebase + v * SBLK + t;
        bool m = (node_map[ei[e]] >= 0) && (node_map[ei[NE + e]] >= 0);
        unsigned long long bal = __ballot(m);
        if (lane == 0) subcnt[v][wave] = __popcll(bal);
    }
    __syncthreads();
    if (t == 0) {
        int cnt = 0;
        #pragma unroll
        for (int v = 0; v < VPT; v++)
            cnt += subcnt[v][0] + subcnt[v][1] + subcnt[v][2] + subcnt[v][3];
        tilecounts[tile] = cnt;
    }
}

// --- 4. exclusive scan of 4096 tile counts (single block) ----------------
__global__ void __launch_bounds__(256)
scan_kernel(const int* __restrict__ tilecounts,
            int* __restrict__ tileoffs) {
    const int PER = NTILE / 256;   // 16
    int t = threadIdx.x;
    int base = t * PER;
    int s = 0;
    #pragma unroll
    for (int j = 0; j < PER; j++) s += tilecounts[base + j];
    __shared__ int ls[256];
    ls[t] = s;
    __syncthreads();
    for (int off = 1; off < 256; off <<= 1) {
        int v = (t >= off) ? ls[t - off] : 0;
        __syncthreads();
        ls[t] += v;
        __syncthreads();
    }
    int run = ls[t] - s;   // exclusive prefix of this thread's chunk
    #pragma unroll
    for (int j = 0; j < PER; j++) {
        int c = tilecounts[base + j];
        tileoffs[base + j] = run;
        run += c;
    }
}

// --- 5. stable scatter of kept edges + fused tail fill -------------------
__global__ void __launch_bounds__(SBLK)
scatter_kernel(const int* __restrict__ ei,
               const float* __restrict__ eattr,
               const int* __restrict__ node_map,
               const int* __restrict__ tileoffs,
               float* __restrict__ out) {
    int tile = blockIdx.x;
    int t = threadIdx.x;
    int wave = t >> 6, lane = t & 63;
    __shared__ int subcnt[VPT][4];

    int ns[VPT], nd[VPT];
    bool m[VPT];
    unsigned long long bal[VPT];
    int ebase = tile * EPB;
    #pragma unroll
    for (int v = 0; v < VPT; v++) {
        int e = ebase + v * SBLK + t;
        int a = ei[e], c = ei[NE + e];
        ns[v] = node_map[a];
        nd[v] = node_map[c];
        m[v] = (ns[v] >= 0) && (nd[v] >= 0);
        bal[v] = __ballot(m[v]);
        if (lane == 0) subcnt[v][wave] = __popcll(bal[v]);
    }
    __syncthreads();
    int cnt = 0;
    #pragma unroll
    for (int v = 0; v < VPT; v++)
        cnt += subcnt[v][0] + subcnt[v][1] + subcnt[v][2] + subcnt[v][3];
    int excl = tileoffs[tile];

    // kept-edge scatter (stable)
    int sub_off = excl;
    #pragma unroll
    for (int v = 0; v < VPT; v++) {
        if (m[v]) {
            int wbase = 0;
            for (int i = 0; i < wave; i++) wbase += subcnt[v][i];
            int lpre = __popcll(bal[v] & ((1ull << lane) - 1ull));
            int pos = sub_off + wbase + lpre;
            out[OUT_EI + pos]      = (float)ns[v];
            out[OUT_EI + NE + pos] = (float)nd[v];
            int e = ebase + v * SBLK + t;
            const float4* sp = (const float4*)(eattr + (size_t)e * DE);
            float4* dp = (float4*)(out + OUT_ATTR + (size_t)pos * DE);
            dp[0] = sp[0]; dp[1] = sp[1]; dp[2] = sp[2]; dp[3] = sp[3];
        }
        sub_off += subcnt[v][0] + subcnt[v][1] + subcnt[v][2] + subcnt[v][3];
    }

    // fused tail fill: this tile's discarded edges own tail slots
    // [NE - disc_excl - disc_cnt, NE - disc_excl)
    int disc_excl = tile * EPB - excl;
    int disc_cnt  = EPB - cnt;
    size_t tail_lo = (size_t)NE - disc_excl - disc_cnt;
    for (int i = t; i < disc_cnt; i += SBLK) {
        out[OUT_EI + tail_lo + i]      = -1.f;
        out[OUT_EI + NE + tail_lo + i] = -1.f;
    }
    float4* ap = (float4*)(out + OUT_ATTR);
    float4 z = make_float4(0.f, 0.f, 0.f, 0.f);
    for (int i = t; i < disc_cnt * 4; i += SBLK)
        ap[tail_lo * 4 + i] = z;
}

extern "C" void kernel_launch(void* const* d_in, const int* in_sizes, int n_in,
                              void* d_out, int out_size, void* d_ws, size_t ws_size,
                              hipStream_t stream) {
    const float* x     = (const float*)d_in[0];
    const int*   ei    = (const int*)d_in[1];
    const float* eattr = (const float*)d_in[2];
    const float* W     = (const float*)d_in[4];
    const float* b     = (const float*)d_in[5];
    float* out = (float*)d_out;

    // workspace layout
    int*   tilecounts = (int*)d_ws;
    int*   tileoffs   = tilecounts + NTILE;
    float* scores     = (float*)(tileoffs + NTILE);
    int*   node_map   = (int*)(scores + NN);

    score_kernel      <<<NN / 8, 256, 0, stream>>>(x, W, b, scores, node_map);
    topk_gather_kernel<<<NGRAPH, NPG, 0, stream>>>(scores, x, node_map, out);
    count_kernel      <<<NTILE, SBLK, 0, stream>>>(ei, node_map, tilecounts);
    scan_kernel       <<<1, 256, 0, stream>>>(tilecounts, tileoffs);
    scatter_kernel    <<<NTILE, SBLK, 0, stream>>>(ei, eattr, node_map, tileoffs, out);
}

// Round 5
// 157.286 us; speedup vs baseline: 1.5994x; 1.4073x over previous
//
#include <hip/hip_runtime.h>

#define NGRAPH 512
#define NPG    256
#define KPG    128
#define NN     (NGRAPH * NPG)   // 131072 nodes
#define KK     (NGRAPH * KPG)   // 65536 kept nodes
#define NE     4194304          // edges
#define DF     128
#define DE     16

#define SBLK   256              // threads per edge block
#define EPB    1024             // edges per tile (4 per thread)
#define NTILE  (NE / EPB)       // 4096 tiles

// output layout (float32 elements, concatenated in reference return order)
#define OUT_X     0ull
#define OUT_EI    ((size_t)KK * DF)                 // 8388608
#define OUT_ATTR  (OUT_EI + 2ull * NE)              // 16777216
#define OUT_BATCH (OUT_ATTR + (size_t)NE * DE)      // 83886080
#define OUT_PERM  (OUT_BATCH + KK)
#define OUT_W     (OUT_PERM + KK)

// --- 1. scores = x @ W + b (float4, 32 lanes/row) ------------------------
__global__ void score_kernel(const float* __restrict__ x,
                             const float* __restrict__ W,
                             const float* __restrict__ b,
                             float* __restrict__ scores) {
    int t = threadIdx.x;
    int l32 = t & 31;
    int node = blockIdx.x * 8 + (t >> 5);
    float4 xv = ((const float4*)(x + (size_t)node * DF))[l32];
    float4 wv = ((const float4*)W)[l32];
    float s = xv.x * wv.x + xv.y * wv.y + xv.z * wv.z + xv.w * wv.w;
    #pragma unroll
    for (int off = 16; off > 0; off >>= 1) s += __shfl_down(s, off, 32);
    if (l32 == 0) scores[node] = s + b[0];
}

// --- 2. fused top-k + gather-scale + node_map + node-kept bits -----------
__global__ void __launch_bounds__(NPG)
topk_gather_kernel(const float* __restrict__ scores,
                   const float* __restrict__ x,
                   int* __restrict__ node_map,
                   unsigned* __restrict__ nkbits,
                   float* __restrict__ out) {
    __shared__ float s[NPG];
    __shared__ int   sel[KPG];      // rank -> local node id
    __shared__ float selw[KPG];     // rank -> score
    int g = blockIdx.x, t = threadIdx.x;
    int wave = t >> 6, lane = t & 63;
    float my = scores[g * NPG + t];
    s[t] = my;
    __syncthreads();
    int rank = 0;
    #pragma unroll 8
    for (int j = 0; j < NPG; j++) {
        float o = s[j];
        rank += (o > my) || (o == my && j < t);
    }
    bool kept = rank < KPG;
    if (kept) {
        int node = g * NPG + t;
        int nid  = g * KPG + rank;
        node_map[node] = nid;
        sel[rank]  = t;
        selw[rank] = my;
        out[OUT_BATCH + nid] = (float)g;
        out[OUT_PERM + nid]  = (float)node;
        out[OUT_W + nid]     = my;
    }
    // node-kept bitmap: word (g*8 + t/32), bit (t&31)
    unsigned long long bal = __ballot(kept);
    if (lane == 0)  nkbits[g * 8 + wave * 2]     = (unsigned)bal;
    if (lane == 32) nkbits[g * 8 + wave * 2 + 1] = (unsigned)(bal >> 32);
    __syncthreads();
    // gather + scale: 8 rows in flight (32 lanes x float4 each), 16 iters
    int l32 = t & 31, rsub = t >> 5;
    #pragma unroll
    for (int it = 0; it < KPG / 8; it++) {
        int r = it * 8 + rsub;
        int node = g * NPG + sel[r];
        float wv = selw[r];
        float4 v = ((const float4*)(x + (size_t)node * DF))[l32];
        v.x *= wv; v.y *= wv; v.z *= wv; v.w *= wv;
        ((float4*)(out + OUT_X + ((size_t)g * KPG + r) * DF))[l32] = v;
    }
}

// --- 3. edge-keep bitmap + per-tile counts (L1-resident nkbits) ----------
__global__ void __launch_bounds__(SBLK)
mapcount_kernel(const int* __restrict__ ei,
                const unsigned* __restrict__ nkbits,
                unsigned* __restrict__ bitmap,
                int* __restrict__ tilecounts) {
    int tile = blockIdx.x, t = threadIdx.x;
    int ebase = tile * EPB + t * 4;
    int4 sv = *(const int4*)(ei + ebase);
    int4 dv = *(const int4*)(ei + NE + ebase);
    #define KB(n) ((nkbits[(unsigned)(n) >> 5] >> ((unsigned)(n) & 31u)) & 1u)
    unsigned bits = (KB(sv.x) & KB(dv.x))
                  | ((KB(sv.y) & KB(dv.y)) << 1)
                  | ((KB(sv.z) & KB(dv.z)) << 2)
                  | ((KB(sv.w) & KB(dv.w)) << 3);
    #undef KB
    __shared__ unsigned nib[SBLK];
    nib[t] = bits;
    __syncthreads();
    if (t < 32) {
        unsigned w = 0;
        #pragma unroll
        for (int k = 0; k < 8; k++) w |= nib[t * 8 + k] << (4 * k);
        bitmap[tile * 32 + t] = w;
        int c = __popc(w);
        #pragma unroll
        for (int off = 16; off > 0; off >>= 1) c += __shfl_down(c, off, 64);
        if (t == 0) tilecounts[tile] = c;
    }
}

// --- 4. exclusive scan of 4096 tile counts (single block) ----------------
__global__ void __launch_bounds__(256)
scan_kernel(const int* __restrict__ tilecounts,
            int* __restrict__ tileoffs) {
    const int PER = NTILE / 256;   // 16
    int t = threadIdx.x;
    int base = t * PER;
    int s = 0;
    #pragma unroll
    for (int j = 0; j < PER; j++) s += tilecounts[base + j];
    __shared__ int ls[256];
    ls[t] = s;
    __syncthreads();
    for (int off = 1; off < 256; off <<= 1) {
        int v = (t >= off) ? ls[t - off] : 0;
        __syncthreads();
        ls[t] += v;
        __syncthreads();
    }
    int run = ls[t] - s;
    #pragma unroll
    for (int j = 0; j < PER; j++) {
        int c = tilecounts[base + j];
        tileoffs[base + j] = run;
        run += c;
    }
}

// --- 5. dense stable scatter + fused tail fill ----------------------------
__global__ void __launch_bounds__(SBLK)
scatter_kernel(const int* __restrict__ ei,
               const float* __restrict__ eattr,
               const int* __restrict__ node_map,
               const unsigned* __restrict__ bitmap,
               const int* __restrict__ tileoffs,
               float* __restrict__ out) {
    int tile = blockIdx.x, t = threadIdx.x;
    int lane = t & 63;
    __shared__ unsigned bmw[32];
    __shared__ int wordpre[32];
    __shared__ int s_cnt;
    __shared__ unsigned pk[EPB];          // (ns<<16)|nd, dense by kept order
    __shared__ unsigned short kl[EPB];    // kept local edge id, dense

    if (t < 32) {
        unsigned w = bitmap[tile * 32 + t];
        bmw[t] = w;
        int c = __popc(w);
        int v = c;
        #pragma unroll
        for (int off = 1; off < 32; off <<= 1) {
            int u = __shfl_up(v, off, 64);
            if (lane >= off) v += u;
        }
        wordpre[t] = v - c;               // exclusive prefix
        if (t == 31) s_cnt = v;
    }
    __syncthreads();
    int cnt = s_cnt;

    // stage kept edges into LDS (4 edges per thread)
    int el0 = t * 4;
    unsigned word = bmw[t >> 3];
    int bit0 = (t & 7) * 4;
    unsigned mybits = (word >> bit0) & 0xFu;
    if (mybits) {
        int pre = wordpre[t >> 3] + __popc(word & ((1u << bit0) - 1u));
        int4 sv = *(const int4*)(ei + tile * EPB + el0);
        int4 dv = *(const int4*)(ei + NE + tile * EPB + el0);
        int s4[4] = {sv.x, sv.y, sv.z, sv.w};
        int d4[4] = {dv.x, dv.y, dv.z, dv.w};
        #pragma unroll
        for (int j = 0; j < 4; j++) {
            if ((mybits >> j) & 1u) {
                unsigned ns = (unsigned)node_map[s4[j]];
                unsigned nd = (unsigned)node_map[d4[j]];
                pk[pre] = (ns << 16) | nd;
                kl[pre] = (unsigned short)(el0 + j);
                pre++;
            }
        }
    }
    __syncthreads();
    int excl = tileoffs[tile];

    // dense new_ei writes
    for (int j = t; j < cnt; j += SBLK) {
        unsigned p = pk[j];
        out[OUT_EI + excl + j]      = (float)(p >> 16);
        out[OUT_EI + NE + excl + j] = (float)(p & 0xFFFFu);
    }
    // dense attr copy: 4 lanes per edge, wave writes 1KB contiguous
    int sub = t & 3;
    for (int j = t >> 2; j < cnt; j += SBLK / 4) {
        int el = kl[j];
        float4 v = ((const float4*)(eattr + ((size_t)tile * EPB + el) * DE))[sub];
        ((float4*)(out + OUT_ATTR + ((size_t)excl + j) * DE))[sub] = v;
    }
    // fused tail fill: this tile's discarded edges own tail slots
    int disc_excl = tile * EPB - excl;
    int disc = EPB - cnt;
    size_t tail_lo = (size_t)NE - disc_excl - disc;
    for (int i = t; i < disc; i += SBLK) {
        out[OUT_EI + tail_lo + i]      = -1.f;
        out[OUT_EI + NE + tail_lo + i] = -1.f;
    }
    float4* ap = (float4*)(out + OUT_ATTR);
    float4 z = make_float4(0.f, 0.f, 0.f, 0.f);
    for (int i = t; i < disc * 4; i += SBLK)
        ap[tail_lo * 4 + i] = z;
}

extern "C" void kernel_launch(void* const* d_in, const int* in_sizes, int n_in,
                              void* d_out, int out_size, void* d_ws, size_t ws_size,
                              hipStream_t stream) {
    const float* x     = (const float*)d_in[0];
    const int*   ei    = (const int*)d_in[1];
    const float* eattr = (const float*)d_in[2];
    const float* W     = (const float*)d_in[4];
    const float* b     = (const float*)d_in[5];
    float* out = (float*)d_out;

    // workspace layout (all 4B types, ~1.6 MB total)
    float*    scores     = (float*)d_ws;
    int*      node_map   = (int*)(scores + NN);
    unsigned* nkbits     = (unsigned*)(node_map + NN);
    unsigned* bitmap     = nkbits + NN / 32;
    int*      tilecounts = (int*)(bitmap + NE / 32);
    int*      tileoffs   = tilecounts + NTILE;

    score_kernel      <<<NN / 8, 256, 0, stream>>>(x, W, b, scores);
    topk_gather_kernel<<<NGRAPH, NPG, 0, stream>>>(scores, x, node_map, nkbits, out);
    mapcount_kernel   <<<NTILE, SBLK, 0, stream>>>(ei, nkbits, bitmap, tilecounts);
    scan_kernel       <<<1, 256, 0, stream>>>(tilecounts, tileoffs);
    scatter_kernel    <<<NTILE, SBLK, 0, stream>>>(ei, eattr, node_map, bitmap, tileoffs, out);
}

// Round 8
// 151.807 us; speedup vs baseline: 1.6572x; 1.0361x over previous
//
#include <hip/hip_runtime.h>

#define NGRAPH 512
#define NPG    256
#define KPG    128
#define NN     (NGRAPH * NPG)   // 131072 nodes
#define KK     (NGRAPH * KPG)   // 65536 kept nodes
#define NE     4194304          // edges
#define DF     128
#define DE     16

#define SBLK   256              // threads per edge block
#define EPB    1024             // edges per tile (4 per thread)
#define NTILE  (NE / EPB)       // 4096 tiles

typedef float vf4 __attribute__((ext_vector_type(4)));

// output layout (float32 elements, concatenated in reference return order)
#define OUT_X     0ull
#define OUT_EI    ((size_t)KK * DF)                 // 8388608
#define OUT_ATTR  (OUT_EI + 2ull * NE)              // 16777216
#define OUT_BATCH (OUT_ATTR + (size_t)NE * DE)      // 83886080
#define OUT_PERM  (OUT_BATCH + KK)
#define OUT_W     (OUT_PERM + KK)

// --- 1. scores = x @ W + b (float4, 32 lanes/row) ------------------------
__global__ void score_kernel(const float* __restrict__ x,
                             const float* __restrict__ W,
                             const float* __restrict__ b,
                             float* __restrict__ scores) {
    int t = threadIdx.x;
    int l32 = t & 31;
    int node = blockIdx.x * 8 + (t >> 5);
    float4 xv = ((const float4*)(x + (size_t)node * DF))[l32];
    float4 wv = ((const float4*)W)[l32];
    float s = xv.x * wv.x + xv.y * wv.y + xv.z * wv.z + xv.w * wv.w;
    #pragma unroll
    for (int off = 16; off > 0; off >>= 1) s += __shfl_down(s, off, 32);
    if (l32 == 0) scores[node] = s + b[0];
}

// --- 2. fused top-k + gather-scale + node_map + node-kept bits -----------
__global__ void __launch_bounds__(NPG)
topk_gather_kernel(const float* __restrict__ scores,
                   const float* __restrict__ x,
                   int* __restrict__ node_map,
                   unsigned* __restrict__ nkbits,
                   float* __restrict__ out) {
    __shared__ float s[NPG];
    __shared__ int   sel[KPG];      // rank -> local node id
    __shared__ float selw[KPG];     // rank -> score
    int g = blockIdx.x, t = threadIdx.x;
    int wave = t >> 6, lane = t & 63;
    float my = scores[g * NPG + t];
    s[t] = my;
    __syncthreads();
    int rank = 0;
    #pragma unroll 8
    for (int j = 0; j < NPG; j++) {
        float o = s[j];
        rank += (o > my) || (o == my && j < t);
    }
    bool kept = rank < KPG;
    if (kept) {
        int node = g * NPG + t;
        int nid  = g * KPG + rank;
        node_map[node] = nid;
        sel[rank]  = t;
        selw[rank] = my;
        out[OUT_BATCH + nid] = (float)g;
        out[OUT_PERM + nid]  = (float)node;
        out[OUT_W + nid]     = my;
    }
    // node-kept bitmap: word (g*8 + t/32), bit (t&31)
    unsigned long long bal = __ballot(kept);
    if (lane == 0)  nkbits[g * 8 + wave * 2]     = (unsigned)bal;
    if (lane == 32) nkbits[g * 8 + wave * 2 + 1] = (unsigned)(bal >> 32);
    __syncthreads();
    // gather + scale: 8 rows in flight (32 lanes x float4 each), 16 iters
    int l32 = t & 31, rsub = t >> 5;
    #pragma unroll
    for (int it = 0; it < KPG / 8; it++) {
        int r = it * 8 + rsub;
        int node = g * NPG + sel[r];
        float wv = selw[r];
        float4 v = ((const float4*)(x + (size_t)node * DF))[l32];
        v.x *= wv; v.y *= wv; v.z *= wv; v.w *= wv;
        ((float4*)(out + OUT_X + ((size_t)g * KPG + r) * DF))[l32] = v;
    }
}

// --- 3. map + stage: read ei ONCE, stage dense pk/kl per tile, count -----
__global__ void __launch_bounds__(SBLK)
mapstage_kernel(const int* __restrict__ ei,
                const int* __restrict__ node_map,
                const unsigned* __restrict__ nkbits,
                unsigned* __restrict__ pk_ws,
                unsigned short* __restrict__ kl_ws,
                int* __restrict__ tilecounts) {
    int tile = blockIdx.x, t = threadIdx.x;
    int wave = t >> 6, lane = t & 63;
    __shared__ int wtot[4];

    int ebase = tile * EPB + t * 4;
    int4 sv = *(const int4*)(ei + ebase);
    int4 dv = *(const int4*)(ei + NE + ebase);
    #define KB(n) ((nkbits[(unsigned)(n) >> 5] >> ((unsigned)(n) & 31u)) & 1u)
    unsigned bits = (KB(sv.x) & KB(dv.x))
                  | ((KB(sv.y) & KB(dv.y)) << 1)
                  | ((KB(sv.z) & KB(dv.z)) << 2)
                  | ((KB(sv.w) & KB(dv.w)) << 3);
    #undef KB
    int c = __popc(bits);
    // block exclusive scan of c
    int inc = c;
    #pragma unroll
    for (int off = 1; off < 64; off <<= 1) {
        int u = __shfl_up(inc, off, 64);
        if (lane >= off) inc += u;
    }
    if (lane == 63) wtot[wave] = inc;
    __syncthreads();
    int wbase = 0;
    #pragma unroll
    for (int i = 0; i < 4; i++) if (i < wave) wbase += wtot[i];
    int pre = wbase + inc - c;

    if (bits) {
        int s4[4] = {sv.x, sv.y, sv.z, sv.w};
        int d4[4] = {dv.x, dv.y, dv.z, dv.w};
        #pragma unroll
        for (int j = 0; j < 4; j++) {
            if ((bits >> j) & 1u) {
                unsigned ns = (unsigned)node_map[s4[j]];
                unsigned nd = (unsigned)node_map[d4[j]];
                pk_ws[tile * EPB + pre] = (ns << 16) | nd;
                kl_ws[tile * EPB + pre] = (unsigned short)(t * 4 + j);
                pre++;
            }
        }
    }
    if (t == 0) tilecounts[tile] = wtot[0] + wtot[1] + wtot[2] + wtot[3];
}

// --- 4. exclusive scan of 4096 tile counts (single block) ----------------
__global__ void __launch_bounds__(256)
scan_kernel(const int* __restrict__ tilecounts,
            int* __restrict__ tileoffs) {
    const int PER = NTILE / 256;   // 16
    int t = threadIdx.x;
    int base = t * PER;
    int s = 0;
    #pragma unroll
    for (int j = 0; j < PER; j++) s += tilecounts[base + j];
    __shared__ int ls[256];
    ls[t] = s;
    __syncthreads();
    for (int off = 1; off < 256; off <<= 1) {
        int v = (t >= off) ? ls[t - off] : 0;
        __syncthreads();
        ls[t] += v;
        __syncthreads();
    }
    int run = ls[t] - s;
    #pragma unroll
    for (int j = 0; j < PER; j++) {
        int c = tilecounts[base + j];
        tileoffs[base + j] = run;
        run += c;
    }
}

// --- 5. pure-streaming scatter + fused tail fill (nontemporal stores) ----
__global__ void __launch_bounds__(SBLK)
scatter_kernel(const float* __restrict__ eattr,
               const unsigned* __restrict__ pk_ws,
               const unsigned short* __restrict__ kl_ws,
               const int* __restrict__ tilecounts,
               const int* __restrict__ tileoffs,
               float* __restrict__ out) {
    int tile = blockIdx.x, t = threadIdx.x;
    int cnt  = tilecounts[tile];
    int excl = tileoffs[tile];

    // dense new_ei writes
    for (int j = t; j < cnt; j += SBLK) {
        unsigned p = pk_ws[tile * EPB + j];
        __builtin_nontemporal_store((float)(p >> 16),     &out[OUT_EI + excl + j]);
        __builtin_nontemporal_store((float)(p & 0xFFFFu), &out[OUT_EI + NE + excl + j]);
    }
    // dense attr copy: 4 lanes per edge (64B row), contiguous 1KB/wave writes
    int sub = t & 3;
    for (int j = t >> 2; j < cnt; j += SBLK / 4) {
        int el = kl_ws[tile * EPB + j];
        const vf4* sp = (const vf4*)(eattr + ((size_t)tile * EPB + el) * DE);
        vf4 v = __builtin_nontemporal_load(sp + sub);
        vf4* dp = (vf4*)(out + OUT_ATTR + ((size_t)excl + j) * DE);
        __builtin_nontemporal_store(v, dp + sub);
    }
    // fused tail fill: this tile's discarded edges own tail slots
    int disc_excl = tile * EPB - excl;
    int disc = EPB - cnt;
    size_t tail_lo = (size_t)NE - disc_excl - disc;
    for (int i = t; i < disc; i += SBLK) {
        __builtin_nontemporal_store(-1.f, &out[OUT_EI + tail_lo + i]);
        __builtin_nontemporal_store(-1.f, &out[OUT_EI + NE + tail_lo + i]);
    }
    vf4* ap = (vf4*)(out + OUT_ATTR);
    vf4 z = (vf4){0.f, 0.f, 0.f, 0.f};
    for (int i = t; i < disc * 4; i += SBLK)
        __builtin_nontemporal_store(z, &ap[tail_lo * 4 + i]);
}

extern "C" void kernel_launch(void* const* d_in, const int* in_sizes, int n_in,
                              void* d_out, int out_size, void* d_ws, size_t ws_size,
                              hipStream_t stream) {
    const float* x     = (const float*)d_in[0];
    const int*   ei    = (const int*)d_in[1];
    const float* eattr = (const float*)d_in[2];
    const float* W     = (const float*)d_in[4];
    const float* b     = (const float*)d_in[5];
    float* out = (float*)d_out;

    // workspace layout (~26.3 MB)
    float*          scores     = (float*)d_ws;
    int*            node_map   = (int*)(scores + NN);
    unsigned*       nkbits     = (unsigned*)(node_map + NN);
    int*            tilecounts = (int*)(nkbits + NN / 32);
    int*            tileoffs   = tilecounts + NTILE;
    unsigned*       pk_ws      = (unsigned*)(tileoffs + NTILE);
    unsigned short* kl_ws      = (unsigned short*)(pk_ws + NE);

    score_kernel      <<<NN / 8, 256, 0, stream>>>(x, W, b, scores);
    topk_gather_kernel<<<NGRAPH, NPG, 0, stream>>>(scores, x, node_map, nkbits, out);
    mapstage_kernel   <<<NTILE, SBLK, 0, stream>>>(ei, node_map, nkbits, pk_ws, kl_ws, tilecounts);
    scan_kernel       <<<1, 256, 0, stream>>>(tilecounts, tileoffs);
    scatter_kernel    <<<NTILE, SBLK, 0, stream>>>(eattr, pk_ws, kl_ws, tilecounts, tileoffs, out);
}

// Round 9
// 151.187 us; speedup vs baseline: 1.6639x; 1.0041x over previous
//
#include <hip/hip_runtime.h>

#define NGRAPH 512
#define NPG    256
#define KPG    128
#define NN     (NGRAPH * NPG)   // 131072 nodes
#define KK     (NGRAPH * KPG)   // 65536 kept nodes
#define NE     4194304          // edges
#define DF     128
#define DE     16

#define SBLK   256              // threads per edge block
#define EPB    1024             // edges per tile (4 per thread)
#define NTILE  (NE / EPB)       // 4096 tiles

typedef float vf4 __attribute__((ext_vector_type(4)));
typedef int   vi4 __attribute__((ext_vector_type(4)));

// output layout (float32 elements, concatenated in reference return order)
#define OUT_X     0ull
#define OUT_EI    ((size_t)KK * DF)                 // 8388608
#define OUT_ATTR  (OUT_EI + 2ull * NE)              // 16777216
#define OUT_BATCH (OUT_ATTR + (size_t)NE * DE)      // 83886080
#define OUT_PERM  (OUT_BATCH + KK)
#define OUT_W     (OUT_PERM + KK)

// --- 1. fused score + top-k + gather-scale + node_map + kept bits --------
__global__ void __launch_bounds__(NPG)
topk_all_kernel(const float* __restrict__ x,
                const float* __restrict__ W,
                const float* __restrict__ b,
                int* __restrict__ node_map,
                unsigned* __restrict__ nkbits,
                float* __restrict__ out) {
    __shared__ float s[NPG];
    __shared__ int   sel[KPG];      // rank -> local node id
    __shared__ float selw[KPG];     // rank -> score
    int g = blockIdx.x, t = threadIdx.x;
    int wave = t >> 6, lane = t & 63;
    int l32 = t & 31, grp = t >> 5;
    float bias = b[0];

    // scores: 8 rows in flight (32 lanes x float4), 32 iters covers 256 rows
    float4 wv = ((const float4*)W)[l32];
    #pragma unroll 4
    for (int it = 0; it < NPG / 8; it++) {
        int r = it * 8 + grp;
        float4 xv = ((const float4*)(x + ((size_t)g * NPG + r) * DF))[l32];
        float sum = xv.x * wv.x + xv.y * wv.y + xv.z * wv.z + xv.w * wv.w;
        #pragma unroll
        for (int off = 16; off > 0; off >>= 1) sum += __shfl_down(sum, off, 32);
        if (l32 == 0) s[r] = sum + bias;
    }
    __syncthreads();
    float my = s[t];
    int rank = 0;
    #pragma unroll 8
    for (int j = 0; j < NPG; j++) {
        float o = s[j];
        rank += (o > my) || (o == my && j < t);
    }
    bool kept = rank < KPG;
    if (kept) {
        int node = g * NPG + t;
        int nid  = g * KPG + rank;
        node_map[node] = nid;
        sel[rank]  = t;
        selw[rank] = my;
        out[OUT_BATCH + nid] = (float)g;
        out[OUT_PERM + nid]  = (float)node;
        out[OUT_W + nid]     = my;
    }
    // node-kept bitmap: word (g*8 + t/32), bit (t&31)
    unsigned long long bal = __ballot(kept);
    if (lane == 0)  nkbits[g * 8 + wave * 2]     = (unsigned)bal;
    if (lane == 32) nkbits[g * 8 + wave * 2 + 1] = (unsigned)(bal >> 32);
    __syncthreads();
    // gather + scale from L2/L3-warm x; nontemporal output stores
    #pragma unroll
    for (int it = 0; it < KPG / 8; it++) {
        int r = it * 8 + grp;
        int node = g * NPG + sel[r];
        float wvs = selw[r];
        const vf4* sp = (const vf4*)(x + (size_t)node * DF);
        vf4 v = sp[l32];
        v *= wvs;
        __builtin_nontemporal_store(v,
            (vf4*)(out + OUT_X + ((size_t)g * KPG + r) * DF) + l32);
    }
}

// --- 2. map + stage: read ei ONCE (NT), stage dense pk/kl, count ---------
__global__ void __launch_bounds__(SBLK)
mapstage_kernel(const int* __restrict__ ei,
                const int* __restrict__ node_map,
                const unsigned* __restrict__ nkbits,
                unsigned* __restrict__ pk_ws,
                unsigned short* __restrict__ kl_ws,
                int* __restrict__ tilecounts) {
    int tile = blockIdx.x, t = threadIdx.x;
    int wave = t >> 6, lane = t & 63;
    __shared__ int wtot[4];

    int ebase = tile * EPB + t * 4;
    vi4 sv = __builtin_nontemporal_load((const vi4*)(ei + ebase));
    vi4 dv = __builtin_nontemporal_load((const vi4*)(ei + NE + ebase));
    #define KB(n) ((nkbits[(unsigned)(n) >> 5] >> ((unsigned)(n) & 31u)) & 1u)
    unsigned bits = (KB(sv.x) & KB(dv.x))
                  | ((KB(sv.y) & KB(dv.y)) << 1)
                  | ((KB(sv.z) & KB(dv.z)) << 2)
                  | ((KB(sv.w) & KB(dv.w)) << 3);
    #undef KB
    int c = __popc(bits);
    // block exclusive scan of c
    int inc = c;
    #pragma unroll
    for (int off = 1; off < 64; off <<= 1) {
        int u = __shfl_up(inc, off, 64);
        if (lane >= off) inc += u;
    }
    if (lane == 63) wtot[wave] = inc;
    __syncthreads();
    int wbase = 0;
    #pragma unroll
    for (int i = 0; i < 4; i++) if (i < wave) wbase += wtot[i];
    int pre = wbase + inc - c;

    if (bits) {
        int s4[4] = {sv.x, sv.y, sv.z, sv.w};
        int d4[4] = {dv.x, dv.y, dv.z, dv.w};
        #pragma unroll
        for (int j = 0; j < 4; j++) {
            if ((bits >> j) & 1u) {
                unsigned ns = (unsigned)node_map[s4[j]];
                unsigned nd = (unsigned)node_map[d4[j]];
                pk_ws[tile * EPB + pre] = (ns << 16) | nd;
                kl_ws[tile * EPB + pre] = (unsigned short)(t * 4 + j);
                pre++;
            }
        }
    }
    if (t == 0) tilecounts[tile] = wtot[0] + wtot[1] + wtot[2] + wtot[3];
}

// --- 3. self-scan + streaming scatter + fused tail fill ------------------
__global__ void __launch_bounds__(SBLK)
scatter_kernel(const float* __restrict__ eattr,
               const unsigned* __restrict__ pk_ws,
               const unsigned short* __restrict__ kl_ws,
               const int* __restrict__ tilecounts,
               float* __restrict__ out) {
    int tile = blockIdx.x, t = threadIdx.x;
    int wave = t >> 6, lane = t & 63;
    __shared__ int warr[4];
    __shared__ int s_excl;

    // self-scan: excl = sum of tilecounts[0..tile)
    int partial = 0;
    for (int i = t; i < tile; i += SBLK) partial += tilecounts[i];
    #pragma unroll
    for (int off = 32; off > 0; off >>= 1) partial += __shfl_down(partial, off, 64);
    if (lane == 0) warr[wave] = partial;
    __syncthreads();
    if (t == 0) s_excl = warr[0] + warr[1] + warr[2] + warr[3];
    __syncthreads();
    int excl = s_excl;
    int cnt  = tilecounts[tile];

    // dense new_ei writes
    for (int j = t; j < cnt; j += SBLK) {
        unsigned p = pk_ws[tile * EPB + j];
        __builtin_nontemporal_store((float)(p >> 16),     &out[OUT_EI + excl + j]);
        __builtin_nontemporal_store((float)(p & 0xFFFFu), &out[OUT_EI + NE + excl + j]);
    }
    // dense attr copy: 4 lanes per edge (64B row), contiguous 1KB/wave writes
    int sub = t & 3;
    for (int j = t >> 2; j < cnt; j += SBLK / 4) {
        int el = kl_ws[tile * EPB + j];
        const vf4* sp = (const vf4*)(eattr + ((size_t)tile * EPB + el) * DE);
        vf4 v = __builtin_nontemporal_load(sp + sub);
        vf4* dp = (vf4*)(out + OUT_ATTR + ((size_t)excl + j) * DE);
        __builtin_nontemporal_store(v, dp + sub);
    }
    // fused tail fill: this tile's discarded edges own tail slots
    int disc_excl = tile * EPB - excl;
    int disc = EPB - cnt;
    size_t tail_lo = (size_t)NE - disc_excl - disc;
    for (int i = t; i < disc; i += SBLK) {
        __builtin_nontemporal_store(-1.f, &out[OUT_EI + tail_lo + i]);
        __builtin_nontemporal_store(-1.f, &out[OUT_EI + NE + tail_lo + i]);
    }
    vf4* ap = (vf4*)(out + OUT_ATTR);
    vf4 z = (vf4){0.f, 0.f, 0.f, 0.f};
    for (int i = t; i < disc * 4; i += SBLK)
        __builtin_nontemporal_store(z, &ap[tail_lo * 4 + i]);
}

extern "C" void kernel_launch(void* const* d_in, const int* in_sizes, int n_in,
                              void* d_out, int out_size, void* d_ws, size_t ws_size,
                              hipStream_t stream) {
    const float* x     = (const float*)d_in[0];
    const int*   ei    = (const int*)d_in[1];
    const float* eattr = (const float*)d_in[2];
    const float* W     = (const float*)d_in[4];
    const float* b     = (const float*)d_in[5];
    float* out = (float*)d_out;

    // workspace layout (~26 MB)
    int*            node_map   = (int*)d_ws;
    unsigned*       nkbits     = (unsigned*)(node_map + NN);
    int*            tilecounts = (int*)(nkbits + NN / 32);
    unsigned*       pk_ws      = (unsigned*)(tilecounts + NTILE);
    unsigned short* kl_ws      = (unsigned short*)(pk_ws + NE);

    topk_all_kernel<<<NGRAPH, NPG, 0, stream>>>(x, W, b, node_map, nkbits, out);
    mapstage_kernel<<<NTILE, SBLK, 0, stream>>>(ei, node_map, nkbits, pk_ws, kl_ws, tilecounts);
    scatter_kernel <<<NTILE, SBLK, 0, stream>>>(eattr, pk_ws, kl_ws, tilecounts, out);
}